// Round 1
// baseline (7836.515 us; speedup 1.0000x reference)
//
#include <hip/hip_runtime.h>
#include <stdint.h>

#define T_STEPS 64
#define BATCH   512
#define OBS_DIM 256
#define ACT_DIM 32
#define HID     1024
#define FEAT    512
#define GDIM    3072
#define KIH     288
#define LOG2PI  1.8378770664093453f

typedef __attribute__((ext_vector_type(8))) short  short8;   // 8 bf16 (4 VGPRs)
typedef __attribute__((ext_vector_type(4))) float  floatx4;  // MFMA C/D frag

__device__ inline float bf2f(unsigned short u) {
    return __uint_as_float(((unsigned int)u) << 16);
}
__device__ inline unsigned short f2bf(float f) {
    unsigned int u = __float_as_uint(f);
    unsigned int r = (u + 0x7FFFu + ((u >> 16) & 1u)) >> 16;  // RNE
    return (unsigned short)r;
}
__device__ inline float elu1(float x)  { return x > 0.f ? x : expm1f(x); }
__device__ inline float sigm(float x)  { return 1.f / (1.f + expf(-x)); }

// ---------------------------------------------------------------------------
// Core 128x128 bf16 NT GEMM tile: C = A[M x K] * W[N x K]^T, K % 32 == 0.
// A, W pre-offset to block origin. LDS rows padded to 40 ushorts (bank safety).
// acc layout per wave (2x2 wave grid): 4x4 frags of 16x16.
// ---------------------------------------------------------------------------
__device__ inline void gemm_core(const unsigned short* __restrict__ A, int lda,
                                 const unsigned short* __restrict__ W, int ldw,
                                 int K,
                                 unsigned short* ldsA, unsigned short* ldsB,
                                 floatx4 acc[4][4])
{
    const int tid  = threadIdx.x;
    const int lane = tid & 63;
    const int wv   = tid >> 6;
    const int wr   = wv & 1;        // wave row (0..1) -> 64 rows
    const int wc   = wv >> 1;       // wave col (0..1) -> 64 cols
    const int fr   = lane & 15;
    const int fq   = lane >> 4;

    for (int k0 = 0; k0 < K; k0 += 32) {
        // stage A and B tiles: 128 rows x 32 bf16 each = 512 chunks of 16B
        for (int c = tid; c < 512; c += 256) {
            int row = c >> 2, ko = (c & 3) << 3;
            *(uint4*)(ldsA + row * 40 + ko) =
                *(const uint4*)(A + (size_t)row * lda + k0 + ko);
            *(uint4*)(ldsB + row * 40 + ko) =
                *(const uint4*)(W + (size_t)row * ldw + k0 + ko);
        }
        __syncthreads();

        short8 af[4], bfg[4];
#pragma unroll
        for (int m = 0; m < 4; ++m)
            af[m] = *(const short8*)(ldsA + (wr * 64 + m * 16 + fr) * 40 + fq * 8);
#pragma unroll
        for (int n = 0; n < 4; ++n)
            bfg[n] = *(const short8*)(ldsB + (wc * 64 + n * 16 + fr) * 40 + fq * 8);
#pragma unroll
        for (int m = 0; m < 4; ++m)
#pragma unroll
            for (int n = 0; n < 4; ++n)
                acc[m][n] = __builtin_amdgcn_mfma_f32_16x16x32_bf16(
                    af[m], bfg[n], acc[m][n], 0, 0, 0);
        __syncthreads();
    }
}

// ---------------------------------------------------------------------------
// S1: C[512 x 4096] = h_bf16[512 x 1024] @ Ws1[4096 x 1024]^T + bias_s1
//     cols < 1024  -> elu -> Z1 (bf16)            (obs/rew layer0)
//     cols >= 1024 -> fp32 -> GH (= h@Whh^T+bhh)  (GRU hidden gates)
// ---------------------------------------------------------------------------
__global__ __launch_bounds__(256) void k_s1(
    const unsigned short* __restrict__ hbf,
    const unsigned short* __restrict__ Ws1,
    const float* __restrict__ bias_s1,
    unsigned short* __restrict__ Z1,
    float* __restrict__ GH)
{
    __shared__ unsigned short ldsA[128 * 40];
    __shared__ unsigned short ldsB[128 * 40];
    floatx4 acc[4][4];
    floatx4 z4 = {0.f, 0.f, 0.f, 0.f};
#pragma unroll
    for (int m = 0; m < 4; ++m)
#pragma unroll
        for (int n = 0; n < 4; ++n) acc[m][n] = z4;

    const int row0 = blockIdx.x * 128;
    const int col0 = blockIdx.y * 128;
    gemm_core(hbf + (size_t)row0 * HID, HID, Ws1 + (size_t)col0 * HID, HID, HID,
              ldsA, ldsB, acc);

    const int lane = threadIdx.x & 63;
    const int wv = threadIdx.x >> 6, wr = wv & 1, wc = wv >> 1;
    const int fr = lane & 15, fq = lane >> 4;
#pragma unroll
    for (int m = 0; m < 4; ++m)
#pragma unroll
        for (int n = 0; n < 4; ++n)
#pragma unroll
            for (int j = 0; j < 4; ++j) {
                int row = row0 + wr * 64 + m * 16 + fq * 4 + j;
                int col = col0 + wc * 64 + n * 16 + fr;
                float v = acc[m][n][j] + bias_s1[col];
                if (col0 < 1024) {
                    Z1[row * HID + col] = f2bf(elu1(v));
                } else {
                    GH[row * GDIM + (col - 1024)] = v;
                }
            }
}

// ---------------------------------------------------------------------------
// S2: Z2 half z = elu(Z1 half z @ W1z^T + b1z), z in {0,1} (obs, rew)
// ---------------------------------------------------------------------------
__global__ __launch_bounds__(256) void k_s2(
    const unsigned short* __restrict__ Z1,
    const unsigned short* __restrict__ W1o,
    const unsigned short* __restrict__ W1r,
    const float* __restrict__ b1o,
    const float* __restrict__ b1r,
    unsigned short* __restrict__ Z2)
{
    __shared__ unsigned short ldsA[128 * 40];
    __shared__ unsigned short ldsB[128 * 40];
    floatx4 acc[4][4];
    floatx4 z4 = {0.f, 0.f, 0.f, 0.f};
#pragma unroll
    for (int m = 0; m < 4; ++m)
#pragma unroll
        for (int n = 0; n < 4; ++n) acc[m][n] = z4;

    const int z    = blockIdx.z;
    const int row0 = blockIdx.x * 128;
    const int col0 = blockIdx.y * 128;
    const unsigned short* A = Z1 + z * FEAT;           // lda = HID
    const unsigned short* W = z ? W1r : W1o;           // ldw = FEAT
    const float* bias = z ? b1r : b1o;

    gemm_core(A + (size_t)row0 * HID, HID, W + (size_t)col0 * FEAT, FEAT, FEAT,
              ldsA, ldsB, acc);

    const int lane = threadIdx.x & 63;
    const int wv = threadIdx.x >> 6, wr = wv & 1, wc = wv >> 1;
    const int fr = lane & 15, fq = lane >> 4;
#pragma unroll
    for (int m = 0; m < 4; ++m)
#pragma unroll
        for (int n = 0; n < 4; ++n)
#pragma unroll
            for (int j = 0; j < 4; ++j) {
                int row = row0 + wr * 64 + m * 16 + fq * 4 + j;
                int col = col0 + wc * 64 + n * 16 + fr;
                float v = acc[m][n][j] + bias[col];
                Z2[row * HID + z * FEAT + col] = f2bf(elu1(v));
            }
}

// ---------------------------------------------------------------------------
// S3: blockIdx.y<2 : obs head GEMM (512x256, K=512 from Z2 obs half)
//       -> pre_obs (fp32 d_out), X_buf[:, :256] (bf16), sq-diff into accum[0]
//     blockIdx.y==2: rew head (dot-512 per row) + act[t] -> X_buf[:, 256:288]
// ---------------------------------------------------------------------------
__global__ __launch_bounds__(256) void k_s3(
    const unsigned short* __restrict__ Z2,
    const unsigned short* __restrict__ W2o,
    const float* __restrict__ b2o,
    const unsigned short* __restrict__ w2r,
    const float* __restrict__ b2r,
    const float* __restrict__ obs,
    const float* __restrict__ reward,
    const float* __restrict__ action,
    unsigned short* __restrict__ Xbuf,
    float* __restrict__ out,
    float* __restrict__ accum,
    int t)
{
    __shared__ unsigned short ldsA[128 * 40];
    __shared__ unsigned short ldsB[128 * 40];

    const int tid  = threadIdx.x;
    const int lane = tid & 63;

    if (blockIdx.y == 2) {
        // ---- special path: act conversion + reward head ----
        const int r0 = blockIdx.x * 128;
        // act[t] -> bf16 X_buf cols 256..287
        for (int e = tid; e < 128 * ACT_DIM; e += 256) {
            int row = r0 + (e >> 5), col = e & 31;
            Xbuf[row * KIH + OBS_DIM + col] =
                f2bf(action[((size_t)t * BATCH + row) * ACT_DIM + col]);
        }
        // reward head: one row per wave-iteration
        const int w = tid >> 6;
        short8 wv8 = *(const short8*)(w2r + lane * 8);
        float wsum = 0.f;
        for (int i = 0; i < 32; ++i) {
            int row = r0 + w * 32 + i;
            short8 zv = *(const short8*)(Z2 + (size_t)row * HID + FEAT + lane * 8);
            float s = 0.f;
#pragma unroll
            for (int j = 0; j < 8; ++j)
                s += bf2f((unsigned short)zv[j]) * bf2f((unsigned short)wv8[j]);
#pragma unroll
            for (int off = 32; off > 0; off >>= 1) s += __shfl_down(s, off, 64);
            if (lane == 0) {
                float m = s + b2r[0];
                out[1 + (size_t)T_STEPS * BATCH * OBS_DIM + (size_t)t * BATCH + row] = m;
                float d = reward[(size_t)t * BATCH + row] - m;
                wsum += d * d;
            }
        }
        if (lane == 0) atomicAdd(accum + 1, wsum);
        return;
    }

    // ---- obs head GEMM path ----
    floatx4 acc[4][4];
    floatx4 z4 = {0.f, 0.f, 0.f, 0.f};
#pragma unroll
    for (int m = 0; m < 4; ++m)
#pragma unroll
        for (int n = 0; n < 4; ++n) acc[m][n] = z4;

    const int row0 = blockIdx.x * 128;
    const int col0 = blockIdx.y * 128;
    gemm_core(Z2 + (size_t)row0 * HID, HID, W2o + (size_t)col0 * FEAT, FEAT, FEAT,
              ldsA, ldsB, acc);

    const int wv = tid >> 6, wr = wv & 1, wc = wv >> 1;
    const int fr = lane & 15, fq = lane >> 4;
    float lsum = 0.f;
#pragma unroll
    for (int m = 0; m < 4; ++m)
#pragma unroll
        for (int n = 0; n < 4; ++n)
#pragma unroll
            for (int j = 0; j < 4; ++j) {
                int row = row0 + wr * 64 + m * 16 + fq * 4 + j;
                int col = col0 + wc * 64 + n * 16 + fr;
                float mval = acc[m][n][j] + b2o[col];
                size_t oidx = (size_t)t * BATCH * OBS_DIM + (size_t)row * OBS_DIM + col;
                out[1 + oidx] = mval;
                Xbuf[row * KIH + col] = f2bf(mval);
                float d = obs[oidx] - mval;
                lsum += d * d;
            }
#pragma unroll
    for (int off = 32; off > 0; off >>= 1) lsum += __shfl_down(lsum, off, 64);
    if (lane == 0) atomicAdd(accum + 0, lsum);
}

// ---------------------------------------------------------------------------
// S4: gi = X[512 x 288] @ Wih[3072 x 288]^T, fused GRU gates -> h, h_bf16.
// Block tile: 128 rows x 64 hid-cols; the r/z/n tiles computed together.
// use_gh==0: h0 path (gh = b_hh, h_prev = 0).
// ---------------------------------------------------------------------------
__global__ __launch_bounds__(256) void k_s4(
    const unsigned short* __restrict__ Xbuf,
    const unsigned short* __restrict__ Wih,
    const float* __restrict__ b_ih,
    const float* __restrict__ b_hh,
    const float* __restrict__ GH,
    float* __restrict__ h,
    unsigned short* __restrict__ hbf,
    int use_gh)
{
    __shared__ unsigned short ldsA[128 * 40];
    __shared__ unsigned short ldsB[3 * 64 * 40];

    floatx4 acc[3][4][2];
    floatx4 z4 = {0.f, 0.f, 0.f, 0.f};
#pragma unroll
    for (int g = 0; g < 3; ++g)
#pragma unroll
        for (int m = 0; m < 4; ++m)
#pragma unroll
            for (int n = 0; n < 2; ++n) acc[g][m][n] = z4;

    const int tid  = threadIdx.x;
    const int lane = tid & 63;
    const int wv   = tid >> 6;
    const int wr   = wv & 1;     // 64-row half
    const int wc   = wv >> 1;    // 32-col half
    const int fr   = lane & 15, fq = lane >> 4;
    const int row0 = blockIdx.x * 128;
    const int col0 = blockIdx.y * 64;

    for (int k0 = 0; k0 < KIH; k0 += 32) {
        for (int c = tid; c < 512; c += 256) {
            int row = c >> 2, ko = (c & 3) << 3;
            *(uint4*)(ldsA + row * 40 + ko) =
                *(const uint4*)(Xbuf + (size_t)(row0 + row) * KIH + k0 + ko);
        }
        for (int c = tid; c < 768; c += 256) {
            int g = c >> 8, rk = c & 255;
            int row = rk >> 2, ko = (rk & 3) << 3;
            *(uint4*)(ldsB + (g * 64 + row) * 40 + ko) =
                *(const uint4*)(Wih + (size_t)(g * HID + col0 + row) * KIH + k0 + ko);
        }
        __syncthreads();

        short8 af[4], bfg[3][2];
#pragma unroll
        for (int m = 0; m < 4; ++m)
            af[m] = *(const short8*)(ldsA + (wr * 64 + m * 16 + fr) * 40 + fq * 8);
#pragma unroll
        for (int g = 0; g < 3; ++g)
#pragma unroll
            for (int n = 0; n < 2; ++n)
                bfg[g][n] = *(const short8*)(ldsB + (g * 64 + wc * 32 + n * 16 + fr) * 40 + fq * 8);
#pragma unroll
        for (int g = 0; g < 3; ++g)
#pragma unroll
            for (int m = 0; m < 4; ++m)
#pragma unroll
                for (int n = 0; n < 2; ++n)
                    acc[g][m][n] = __builtin_amdgcn_mfma_f32_16x16x32_bf16(
                        af[m], bfg[g][n], acc[g][m][n], 0, 0, 0);
        __syncthreads();
    }

#pragma unroll
    for (int m = 0; m < 4; ++m)
#pragma unroll
        for (int n = 0; n < 2; ++n)
#pragma unroll
            for (int j = 0; j < 4; ++j) {
                int row = row0 + wr * 64 + m * 16 + fq * 4 + j;
                int col = col0 + wc * 32 + n * 16 + fr;
                float gr = acc[0][m][n][j] + b_ih[col];
                float gz = acc[1][m][n][j] + b_ih[HID + col];
                float gn = acc[2][m][n][j] + b_ih[2 * HID + col];
                float hr, hz, hn, hp;
                if (use_gh) {
                    hr = GH[(size_t)row * GDIM + col];
                    hz = GH[(size_t)row * GDIM + HID + col];
                    hn = GH[(size_t)row * GDIM + 2 * HID + col];
                    hp = h[(size_t)row * HID + col];
                } else {
                    hr = b_hh[col];
                    hz = b_hh[HID + col];
                    hn = b_hh[2 * HID + col];
                    hp = 0.f;
                }
                float r  = sigm(gr + hr);
                float z  = sigm(gz + hz);
                float nn = tanhf(gn + r * hn);
                float hv = (1.f - z) * nn + z * hp;
                h[(size_t)row * HID + col]   = hv;
                hbf[(size_t)row * HID + col] = f2bf(hv);
            }
}

// ---------------------------------------------------------------------------
// weight conversion fp32 -> bf16 (+ bias_s1 assembly), once per call
// ---------------------------------------------------------------------------
__global__ void k_convert(
    const float* __restrict__ ow0, const float* __restrict__ rw0,
    const float* __restrict__ whh, const float* __restrict__ wih,
    const float* __restrict__ ow1, const float* __restrict__ rw1,
    const float* __restrict__ ow2, const float* __restrict__ rw2,
    const float* __restrict__ ob0, const float* __restrict__ rb0,
    const float* __restrict__ bhh,
    unsigned short* __restrict__ Ws1, unsigned short* __restrict__ Wih,
    unsigned short* __restrict__ W1o, unsigned short* __restrict__ W1r,
    unsigned short* __restrict__ W2o, unsigned short* __restrict__ w2r,
    float* __restrict__ bias_s1)
{
    const int i0 = blockIdx.x * 256 + threadIdx.x;
    const int stride = gridDim.x * 256;
    for (int i = i0; i < 4096 * 1024; i += stride) {
        int row = i >> 10;
        float v = (row < 512) ? ow0[i]
                : (row < 1024) ? rw0[i - 512 * 1024]
                               : whh[i - 1024 * 1024];
        Ws1[i] = f2bf(v);
    }
    for (int i = i0; i < GDIM * KIH; i += stride) Wih[i] = f2bf(wih[i]);
    for (int i = i0; i < FEAT * FEAT; i += stride) {
        W1o[i] = f2bf(ow1[i]);
        W1r[i] = f2bf(rw1[i]);
    }
    for (int i = i0; i < OBS_DIM * FEAT; i += stride) W2o[i] = f2bf(ow2[i]);
    for (int i = i0; i < FEAT; i += stride) w2r[i] = f2bf(rw2[i]);
    for (int i = i0; i < 4096; i += stride)
        bias_s1[i] = (i < 512) ? ob0[i] : (i < 1024) ? rb0[i - 512] : bhh[i - 1024];
}

// X_buf init for h0 step: [bf16(obs[0]) | 0], and zero the loss accumulators
__global__ void k_init(const float* __restrict__ obs,
                       unsigned short* __restrict__ Xbuf,
                       float* __restrict__ accum)
{
    int i = blockIdx.x * 256 + threadIdx.x;
    if (i < BATCH * KIH) {
        int row = i / KIH, col = i - row * KIH;
        Xbuf[i] = (col < OBS_DIM) ? f2bf(obs[row * OBS_DIM + col]) : (unsigned short)0;
    }
    if (i < 2) accum[i] = 0.f;
}

__global__ void k_loss(const float* __restrict__ accum, float* __restrict__ out)
{
    if (threadIdx.x == 0 && blockIdx.x == 0) {
        const float inv = 1.f / (float)(T_STEPS * BATCH);
        out[0] = 0.5f * accum[0] * inv + 128.f * LOG2PI
               + 0.5f * accum[1] * inv + 0.5f * LOG2PI;
    }
}

// ---------------------------------------------------------------------------
extern "C" void kernel_launch(void* const* d_in, const int* in_sizes, int n_in,
                              void* d_out, int out_size, void* d_ws, size_t ws_size,
                              hipStream_t stream)
{
    const float* obs      = (const float*)d_in[0];
    const float* action   = (const float*)d_in[1];
    const float* reward   = (const float*)d_in[2];
    const float* gru_w_ih = (const float*)d_in[3];
    const float* gru_w_hh = (const float*)d_in[4];
    const float* gru_b_ih = (const float*)d_in[5];
    const float* gru_b_hh = (const float*)d_in[6];
    const float* obs_w0   = (const float*)d_in[7];
    const float* obs_b0   = (const float*)d_in[8];
    const float* obs_w1   = (const float*)d_in[9];
    const float* obs_b1   = (const float*)d_in[10];
    const float* obs_w2   = (const float*)d_in[11];
    const float* obs_b2   = (const float*)d_in[12];
    const float* rew_w0   = (const float*)d_in[13];
    const float* rew_b0   = (const float*)d_in[14];
    const float* rew_w1   = (const float*)d_in[15];
    const float* rew_b1   = (const float*)d_in[16];
    const float* rew_w2   = (const float*)d_in[17];
    const float* rew_b2   = (const float*)d_in[18];
    float* out = (float*)d_out;

    char* ws = (char*)d_ws;
    auto alloc = [&](size_t bytes) -> char* {
        char* p = ws;
        ws += (bytes + 255) & ~(size_t)255;
        return p;
    };
    unsigned short* Ws1     = (unsigned short*)alloc((size_t)4096 * 1024 * 2);
    unsigned short* Wih     = (unsigned short*)alloc((size_t)GDIM * KIH * 2);
    unsigned short* W1o     = (unsigned short*)alloc((size_t)FEAT * FEAT * 2);
    unsigned short* W1r     = (unsigned short*)alloc((size_t)FEAT * FEAT * 2);
    unsigned short* W2o     = (unsigned short*)alloc((size_t)OBS_DIM * FEAT * 2);
    unsigned short* w2r     = (unsigned short*)alloc((size_t)FEAT * 2);
    float*          bias_s1 = (float*)alloc((size_t)4096 * 4);
    unsigned short* Z1      = (unsigned short*)alloc((size_t)BATCH * HID * 2);
    unsigned short* Z2      = (unsigned short*)alloc((size_t)BATCH * HID * 2);
    float*          GH      = (float*)alloc((size_t)BATCH * GDIM * 4);
    unsigned short* Xbuf    = (unsigned short*)alloc((size_t)BATCH * KIH * 2);
    float*          h       = (float*)alloc((size_t)BATCH * HID * 4);
    unsigned short* hbf     = (unsigned short*)alloc((size_t)BATCH * HID * 2);
    float*          accum   = (float*)alloc(16);

    dim3 blk(256);

    k_convert<<<dim3(1024), blk, 0, stream>>>(
        obs_w0, rew_w0, gru_w_hh, gru_w_ih, obs_w1, rew_w1, obs_w2, rew_w2,
        obs_b0, rew_b0, gru_b_hh, Ws1, Wih, W1o, W1r, W2o, w2r, bias_s1);

    k_init<<<dim3((BATCH * KIH + 255) / 256), blk, 0, stream>>>(obs, Xbuf, accum);

    // h0 = GRU([obs0, 0], h=0)
    k_s4<<<dim3(4, 16), blk, 0, stream>>>(Xbuf, Wih, gru_b_ih, gru_b_hh, GH, h, hbf, 0);

    for (int t = 0; t < T_STEPS; ++t) {
        k_s1<<<dim3(4, 32), blk, 0, stream>>>(hbf, Ws1, bias_s1, Z1, GH);
        k_s2<<<dim3(4, 4, 2), blk, 0, stream>>>(Z1, W1o, W1r, obs_b1, rew_b1, Z2);
        k_s3<<<dim3(4, 3), blk, 0, stream>>>(Z2, W2o, obs_b2, w2r, rew_b2,
                                             obs, reward, action, Xbuf, out, accum, t);
        if (t < T_STEPS - 1)
            k_s4<<<dim3(4, 16), blk, 0, stream>>>(Xbuf, Wih, gru_b_ih, gru_b_hh,
                                                  GH, h, hbf, 1);
    }

    k_loss<<<dim3(1), blk, 0, stream>>>(accum, out);
}